// Round 1
// baseline (525.045 us; speedup 1.0000x reference)
//
#include <hip/hip_runtime.h>
#include <hip/hip_cooperative_groups.h>

namespace cg = cooperative_groups;

constexpr int TPB   = 256;
constexpr int ITEMS = 31;
constexpr int TILE  = TPB * ITEMS;   // 7936 elements per block
constexpr int GRID  = 1024;          // GRID*TILE = 8,126,464 >= 8,000,000

// Clamp monoid: f(x) = min(max(x + A, B), C), min applied LAST.
// compose(left,right) (left applied first):
//   A = Al + Ar;  B = max(Bl + Ar, Br);  C = min(max(Cl + Ar, Br), Cr)
// Affine monoid for B-bucket: B_out = P*B_in + Q
//   compose(left,right): P = Pl*Pr; Q = Pr*Ql + Qr

__global__ __launch_bounds__(TPB, 4)
void awbm_kernel(const float* __restrict__ x,
                 const float* __restrict__ pBFI,
                 const float* __restrict__ pK,
                 const float* __restrict__ pSmax,
                 float* __restrict__ out,
                 int T)
{
    __shared__ __align__(16) float lds[TILE + 3 * TPB];
    float* lds_d = lds;             // per-element d, later reused as out_partial
    float* sA = lds + TILE;         // scan arrays (256 each)
    float* sB = sA + TPB;
    float* sC = sB + TPB;

    const int tid = threadIdx.x;
    const int b   = blockIdx.x;

    const float bfi  = pBFI[0];
    const float k    = pK[0];
    const float smax = pSmax[0];
    const float omb  = 1.0f - bfi;
    const float omk  = 1.0f - k;
    const float INF  = __builtin_inff();

    // scratch lives in the head of `out`; final outputs overwrite it after sync #3
    float* scrA = out;
    float* scrB = out + GRID;
    float* scrC = out + 2 * GRID;
    float* scrP = out + 3 * GRID;
    float* scrQ = out + 4 * GRID;

    const int gbase = b * TILE;
    cg::grid_group grid = cg::this_grid();

    // ---- stage x -> d in LDS (the ONLY read of x) ----
    {
        const float4* x4 = (const float4*)x;   // two (p,e) pairs per float4
        float2* d2 = (float2*)lds_d;
        for (int i = tid; i < TILE / 2; i += TPB) {
            int e = gbase + 2 * i;
            float2 dv; dv.x = 0.f; dv.y = 0.f;
            if (e < T) {                       // T even, gbase even => pair fully in-range
                float4 v = x4[(gbase >> 1) + i];
                dv.x = v.x - v.y;
                dv.y = v.z - v.w;
            }
            d2[i] = dv;
        }
    }
    __syncthreads();

    const int toff = tid * ITEMS;
    int m = T - gbase - toff;
    m = m < 0 ? 0 : (m > ITEMS ? ITEMS : m);

    // ---- Phase A: per-thread clamp compose, then block scan ----
    float rA = 0.f, rB = -INF, rC = INF;
    if (m == ITEMS) {
#pragma unroll
        for (int j = 0; j < ITEMS; ++j) {
            float d = lds_d[toff + j];
            rA += d;
            rB = fmaxf(rB + d, 0.f);
            rC = fminf(fmaxf(rC + d, 0.f), smax);
        }
    } else {
        for (int j = 0; j < m; ++j) {
            float d = lds_d[toff + j];
            rA += d;
            rB = fmaxf(rB + d, 0.f);
            rC = fminf(fmaxf(rC + d, 0.f), smax);
        }
    }
    sA[tid] = rA; sB[tid] = rB; sC[tid] = rC;
    __syncthreads();
    for (int s = 1; s < TPB; s <<= 1) {
        float pA = 0.f, pB = 0.f, pC = 0.f;
        const bool has = (tid >= s);
        if (has) { pA = sA[tid - s]; pB = sB[tid - s]; pC = sC[tid - s]; }
        __syncthreads();
        if (has) {
            float nA = pA + rA;
            float nB = fmaxf(pB + rA, rB);
            float nC = fminf(fmaxf(pC + rA, rB), rC);
            rA = nA; rB = nB; rC = nC;
            sA[tid] = rA; sB[tid] = rB; sC[tid] = rC;
        }
        __syncthreads();
    }
    float eA = 0.f, eB = -INF, eC = INF;      // exclusive in-block prefix
    if (tid > 0) { eA = sA[tid - 1]; eB = sB[tid - 1]; eC = sC[tid - 1]; }
    if (tid == 0) { scrA[b] = sA[TPB - 1]; scrB[b] = sB[TPB - 1]; scrC[b] = sC[TPB - 1]; }
    __threadfence();
    grid.sync();   // ---- sync 1 ----

    // ---- Phase B: cross-block S scan (computed redundantly in every block) ----
    float hA = 0.f, hB = -INF, hC = INF;
    {
        const int ix = 4 * tid;
#pragma unroll
        for (int q = 0; q < 4; ++q) {
            float ga = scrA[ix + q], gb = scrB[ix + q], gc = scrC[ix + q];
            float nA = hA + ga;
            float nB = fmaxf(hB + ga, gb);
            float nC = fminf(fmaxf(hC + ga, gb), gc);
            hA = nA; hB = nB; hC = nC;
        }
    }
    sA[tid] = hA; sB[tid] = hB; sC[tid] = hC;
    __syncthreads();
    for (int s = 1; s < TPB; s <<= 1) {
        float pA = 0.f, pB = 0.f, pC = 0.f;
        const bool has = (tid >= s);
        if (has) { pA = sA[tid - s]; pB = sB[tid - s]; pC = sC[tid - s]; }
        __syncthreads();
        if (has) {
            float nA = pA + hA;
            float nB = fmaxf(pB + hA, hB);
            float nC = fminf(fmaxf(pC + hA, hB), hC);
            hA = nA; hB = nB; hC = nC;
            sA[tid] = hA; sB[tid] = hB; sC[tid] = hC;
        }
        __syncthreads();
    }
    float S;
    {
        float fA = 0.f, fB = -INF, fC = INF;
        const int g = b >> 2, r = b & 3;
        if (g > 0) { fA = sA[g - 1]; fB = sB[g - 1]; fC = sC[g - 1]; }
        for (int q = 0; q < r; ++q) {          // uniform scalar loads
            float ga = scrA[4 * g + q], gb = scrB[4 * g + q], gc = scrC[4 * g + q];
            float nA = fA + ga;
            float nB = fmaxf(fB + ga, gb);
            float nC = fminf(fmaxf(fC + ga, gb), gc);
            fA = nA; fB = nB; fC = nC;
        }
        S = fminf(fmaxf(0.5f + fA, fB), fC);   // S_INIT = 0.5 -> S at block start
        S = fminf(fmaxf(S + eA, eB), eC);      // S at thread start
    }

    // ---- Phase C: sequential walk; out_partial into LDS; B-affine per thread ----
    float p = 1.f, c = 0.f;
    if (m == ITEMS) {
#pragma unroll
        for (int j = 0; j < ITEMS; ++j) {
            float d  = lds_d[toff + j];
            float S1 = fmaxf(S + d, 0.f);
            float ex = fmaxf(S1 - smax, 0.f);
            S = S1 - ex;
            float w = c + bfi * ex;            // c_j + bfi*ex  (B_t minus k^j*B0 part)
            lds_d[toff + j] = omb * ex + omk * w;
            c = k * w;
            p *= k;
        }
    } else {
        for (int j = 0; j < m; ++j) {
            float d  = lds_d[toff + j];
            float S1 = fmaxf(S + d, 0.f);
            float ex = fmaxf(S1 - smax, 0.f);
            S = S1 - ex;
            float w = c + bfi * ex;
            lds_d[toff + j] = omb * ex + omk * w;
            c = k * w;
            p *= k;
        }
    }
    __syncthreads();   // all phase-B reads of sA/sB done before reuse
    sA[tid] = p; sB[tid] = c;
    __syncthreads();
    for (int s = 1; s < TPB; s <<= 1) {
        float pp = 0.f, pc = 0.f;
        const bool has = (tid >= s);
        if (has) { pp = sA[tid - s]; pc = sB[tid - s]; }
        __syncthreads();
        if (has) {
            float np = pp * p;
            float nc = p * pc + c;
            p = np; c = nc;
            sA[tid] = p; sB[tid] = c;
        }
        __syncthreads();
    }
    float eP = 1.f, eQ = 0.f;
    if (tid > 0) { eP = sA[tid - 1]; eQ = sB[tid - 1]; }
    if (tid == 0) { scrP[b] = sA[TPB - 1]; scrQ[b] = sB[TPB - 1]; }
    __threadfence();
    grid.sync();   // ---- sync 2 ----

    // ---- Phase D: cross-block B scan (redundant) ----
    float hP = 1.f, hQ = 0.f;
    {
        const int ix = 4 * tid;
#pragma unroll
        for (int q = 0; q < 4; ++q) {
            float gp = scrP[ix + q], gq = scrQ[ix + q];
            hQ = gp * hQ + gq;
            hP = hP * gp;
        }
    }
    sA[tid] = hP; sB[tid] = hQ;
    __syncthreads();
    for (int s = 1; s < TPB; s <<= 1) {
        float pp = 0.f, pc = 0.f;
        const bool has = (tid >= s);
        if (has) { pp = sA[tid - s]; pc = sB[tid - s]; }
        __syncthreads();
        if (has) {
            float np = pp * hP;
            float nc = hP * pc + hQ;
            hP = np; hQ = nc;
            sA[tid] = hP; sB[tid] = hQ;
        }
        __syncthreads();
    }
    float Bst;
    {
        float fP = 1.f, fQ = 0.f;
        const int g = b >> 2, r = b & 3;
        if (g > 0) { fP = sA[g - 1]; fQ = sB[g - 1]; }
        for (int q = 0; q < r; ++q) {
            float gp = scrP[4 * g + q], gq = scrQ[4 * g + q];
            fQ = gp * fQ + gq;
            fP *= gp;
        }
        Bst = fP * 1.0f + fQ;    // B_INIT = 1.0 -> B at block start
        Bst = eP * Bst + eQ;     // B at thread start
    }
    grid.sync();   // ---- sync 3: scratch (head of out) fully consumed ----

    // ---- Phase E: add (1-k)*k^j*B_start, coalesced store ----
    float f = omk * Bst;
    if (m == ITEMS) {
#pragma unroll
        for (int j = 0; j < ITEMS; ++j) { lds_d[toff + j] += f; f *= k; }
    } else {
        for (int j = 0; j < m; ++j) { lds_d[toff + j] += f; f *= k; }
    }
    __syncthreads();
    {
        float4* out4 = (float4*)out;
        const float4* l4 = (const float4*)lds_d;
        for (int i = tid; i < TILE / 4; i += TPB) {
            int e = gbase + 4 * i;
            if (e < T) out4[(gbase >> 2) + i] = l4[i];   // T%4==0, gbase%4==0
        }
    }
}

extern "C" void kernel_launch(void* const* d_in, const int* in_sizes, int n_in,
                              void* d_out, int out_size, void* d_ws, size_t ws_size,
                              hipStream_t stream) {
    const float* x    = (const float*)d_in[0];
    const float* BFI  = (const float*)d_in[1];
    const float* K    = (const float*)d_in[2];
    const float* Smax = (const float*)d_in[3];
    float* out = (float*)d_out;
    int T = out_size;   // 8,000,000

    void* args[] = { (void*)&x, (void*)&BFI, (void*)&K, (void*)&Smax, (void*)&out, (void*)&T };
    hipLaunchCooperativeKernel(awbm_kernel, dim3(GRID), dim3(TPB), args, 0, stream);
}

// Round 2
// 240.250 us; speedup vs baseline: 2.1854x; 2.1854x over previous
//
#include <hip/hip_runtime.h>

constexpr int TPB   = 256;
constexpr int ITEMS = 31;
constexpr int TILE  = TPB * ITEMS;   // 7936 elements per block
constexpr int GRID  = 1024;          // GRID*TILE = 8,126,464 >= 8,000,000
constexpr unsigned MAGIC = 0xC0DE600Du;   // != 0xAAAAAAAA ws-poison, != 0

// Clamp monoid: f(x) = min(max(x + A, B), C), min applied LAST.
// compose(left,right) (left applied first):
//   A = Al + Ar;  B = max(Bl + Ar, Br);  C = min(max(Cl + Ar, Br), Cr)
// Affine monoid for B-bucket: B_out = P*B_in + Q
//   compose(left,right): P = Pl*Pr; Q = Pr*Ql + Qr

#define AT_LOAD(p)    __hip_atomic_load((p), __ATOMIC_RELAXED, __HIP_MEMORY_SCOPE_AGENT)
#define AT_STORE(p,v) __hip_atomic_store((p), (v), __ATOMIC_RELAXED, __HIP_MEMORY_SCOPE_AGENT)

// Wait until flags f[0..b) are all MAGIC. Thread `tid` owns indices 4*tid..4*tid+3.
// Publish-before-poll + cooperative launch (all blocks resident) => deadlock-free.
__device__ __forceinline__ void wait_flags(const unsigned* f, int b, int tid) {
    const int base = 4 * tid;
    unsigned need = 0;
#pragma unroll
    for (int q = 0; q < 4; ++q) if (base + q < b) need |= (1u << q);
    while (need) {
        unsigned got = 0;
#pragma unroll
        for (int q = 0; q < 4; ++q)
            if ((need >> q) & 1u)
                if (__hip_atomic_load(&f[base + q], __ATOMIC_RELAXED,
                                      __HIP_MEMORY_SCOPE_AGENT) == MAGIC)
                    got |= (1u << q);
        need &= ~got;
        if (need) __builtin_amdgcn_s_sleep(1);
    }
    __builtin_amdgcn_fence(__ATOMIC_ACQUIRE, "agent");
}

__global__ __launch_bounds__(TPB, 4)
void awbm_kernel(const float* __restrict__ x,
                 const float* __restrict__ pBFI,
                 const float* __restrict__ pK,
                 const float* __restrict__ pSmax,
                 float* __restrict__ out,
                 float* __restrict__ ws,
                 int T)
{
    __shared__ __align__(16) float lds[TILE + 3 * TPB];
    float* lds_d = lds;             // per-element d, later reused as out_partial
    float* sA = lds + TILE;         // scan arrays (256 each)
    float* sB = sA + TPB;
    float* sC = sB + TPB;

    const int tid = threadIdx.x;
    const int b   = blockIdx.x;

    const float bfi  = pBFI[0];
    const float k    = pK[0];
    const float smax = pSmax[0];
    const float omb  = 1.0f - bfi;
    const float omk  = 1.0f - k;
    const float INF  = __builtin_inff();

    // scratch + flags in d_ws (28 KB): never aliases `out` -> no 3rd sync needed
    float* scrA = ws;
    float* scrB = ws + GRID;
    float* scrC = ws + 2 * GRID;
    float* scrP = ws + 3 * GRID;
    float* scrQ = ws + 4 * GRID;
    unsigned* f1 = (unsigned*)(ws + 5 * GRID);
    unsigned* f2 = (unsigned*)(ws + 6 * GRID);

    const int gbase = b * TILE;

    // ---- stage x -> d in LDS (the ONLY read of x) ----
    {
        const float4* x4 = (const float4*)x;   // two (p,e) pairs per float4
        float2* d2 = (float2*)lds_d;
        for (int i = tid; i < TILE / 2; i += TPB) {
            int e = gbase + 2 * i;
            float2 dv; dv.x = 0.f; dv.y = 0.f;
            if (e < T) {                       // T even, gbase even => pair fully in-range
                float4 v = x4[(gbase >> 1) + i];
                dv.x = v.x - v.y;
                dv.y = v.z - v.w;
            }
            d2[i] = dv;
        }
    }
    __syncthreads();

    const int toff = tid * ITEMS;
    int m = T - gbase - toff;
    m = m < 0 ? 0 : (m > ITEMS ? ITEMS : m);

    // ---- Phase A: per-thread clamp compose, then block scan ----
    float rA = 0.f, rB = -INF, rC = INF;
    if (m == ITEMS) {
#pragma unroll
        for (int j = 0; j < ITEMS; ++j) {
            float d = lds_d[toff + j];
            rA += d;
            rB = fmaxf(rB + d, 0.f);
            rC = fminf(fmaxf(rC + d, 0.f), smax);
        }
    } else {
        for (int j = 0; j < m; ++j) {
            float d = lds_d[toff + j];
            rA += d;
            rB = fmaxf(rB + d, 0.f);
            rC = fminf(fmaxf(rC + d, 0.f), smax);
        }
    }
    sA[tid] = rA; sB[tid] = rB; sC[tid] = rC;
    __syncthreads();
    for (int s = 1; s < TPB; s <<= 1) {
        float pA = 0.f, pB = 0.f, pC = 0.f;
        const bool has = (tid >= s);
        if (has) { pA = sA[tid - s]; pB = sB[tid - s]; pC = sC[tid - s]; }
        __syncthreads();
        if (has) {
            float nA = pA + rA;
            float nB = fmaxf(pB + rA, rB);
            float nC = fminf(fmaxf(pC + rA, rB), rC);
            rA = nA; rB = nB; rC = nC;
            sA[tid] = rA; sB[tid] = rB; sC[tid] = rC;
        }
        __syncthreads();
    }
    float eA = 0.f, eB = -INF, eC = INF;      // exclusive in-block prefix
    if (tid > 0) { eA = sA[tid - 1]; eB = sB[tid - 1]; eC = sC[tid - 1]; }
    if (tid == TPB - 1) {                     // registers hold the block aggregate
        AT_STORE(&scrA[b], rA); AT_STORE(&scrB[b], rB); AT_STORE(&scrC[b], rC);
        __hip_atomic_store(&f1[b], MAGIC, __ATOMIC_RELEASE, __HIP_MEMORY_SCOPE_AGENT);
    }
    __syncthreads();            // sA/sB/sC reads done before phase-B overwrites
    wait_flags(f1, b, tid);     // ---- sync 1 (predecessors only) ----

    // ---- Phase B: cross-block S scan; lanes >= b compose garbage, unused ----
    float hA = 0.f, hB = -INF, hC = INF;
    {
        const int ix = 4 * tid;
#pragma unroll
        for (int q = 0; q < 4; ++q) {
            float ga = AT_LOAD(&scrA[ix + q]);
            float gb = AT_LOAD(&scrB[ix + q]);
            float gc = AT_LOAD(&scrC[ix + q]);
            float nA = hA + ga;
            float nB = fmaxf(hB + ga, gb);
            float nC = fminf(fmaxf(hC + ga, gb), gc);
            hA = nA; hB = nB; hC = nC;
        }
    }
    sA[tid] = hA; sB[tid] = hB; sC[tid] = hC;
    __syncthreads();
    for (int s = 1; s < TPB; s <<= 1) {
        float pA = 0.f, pB = 0.f, pC = 0.f;
        const bool has = (tid >= s);
        if (has) { pA = sA[tid - s]; pB = sB[tid - s]; pC = sC[tid - s]; }
        __syncthreads();
        if (has) {
            float nA = pA + hA;
            float nB = fmaxf(pB + hA, hB);
            float nC = fminf(fmaxf(pC + hA, hB), hC);
            hA = nA; hB = nB; hC = nC;
            sA[tid] = hA; sB[tid] = hB; sC[tid] = hC;
        }
        __syncthreads();
    }
    float S;
    {
        float fA = 0.f, fB = -INF, fC = INF;
        const int g = b >> 2, r = b & 3;
        if (g > 0) { fA = sA[g - 1]; fB = sB[g - 1]; fC = sC[g - 1]; }
        for (int q = 0; q < r; ++q) {
            float ga = AT_LOAD(&scrA[4 * g + q]);
            float gb = AT_LOAD(&scrB[4 * g + q]);
            float gc = AT_LOAD(&scrC[4 * g + q]);
            float nA = fA + ga;
            float nB = fmaxf(fB + ga, gb);
            float nC = fminf(fmaxf(fC + ga, gb), gc);
            fA = nA; fB = nB; fC = nC;
        }
        S = fminf(fmaxf(0.5f + fA, fB), fC);   // S_INIT = 0.5 -> S at block start
        S = fminf(fmaxf(S + eA, eB), eC);      // S at thread start
    }

    // ---- Phase C: sequential walk; out_partial into LDS; B-affine per thread ----
    float p = 1.f, c = 0.f;
    if (m == ITEMS) {
#pragma unroll
        for (int j = 0; j < ITEMS; ++j) {
            float d  = lds_d[toff + j];
            float S1 = fmaxf(S + d, 0.f);
            float ex = fmaxf(S1 - smax, 0.f);
            S = S1 - ex;
            float w = c + bfi * ex;            // c_j + bfi*ex  (B_t minus k^j*B0 part)
            lds_d[toff + j] = omb * ex + omk * w;
            c = k * w;
            p *= k;
        }
    } else {
        for (int j = 0; j < m; ++j) {
            float d  = lds_d[toff + j];
            float S1 = fmaxf(S + d, 0.f);
            float ex = fmaxf(S1 - smax, 0.f);
            S = S1 - ex;
            float w = c + bfi * ex;
            lds_d[toff + j] = omb * ex + omk * w;
            c = k * w;
            p *= k;
        }
    }
    __syncthreads();   // all phase-B reads of sA/sB/sC done before reuse
    sA[tid] = p; sB[tid] = c;
    __syncthreads();
    for (int s = 1; s < TPB; s <<= 1) {
        float pp = 0.f, pc = 0.f;
        const bool has = (tid >= s);
        if (has) { pp = sA[tid - s]; pc = sB[tid - s]; }
        __syncthreads();
        if (has) {
            float np = pp * p;
            float nc = p * pc + c;
            p = np; c = nc;
            sA[tid] = p; sB[tid] = c;
        }
        __syncthreads();
    }
    float eP = 1.f, eQ = 0.f;
    if (tid > 0) { eP = sA[tid - 1]; eQ = sB[tid - 1]; }
    if (tid == TPB - 1) {                     // registers hold block affine aggregate
        AT_STORE(&scrP[b], p); AT_STORE(&scrQ[b], c);
        __hip_atomic_store(&f2[b], MAGIC, __ATOMIC_RELEASE, __HIP_MEMORY_SCOPE_AGENT);
    }
    __syncthreads();            // sA/sB reads done before phase-D overwrites
    wait_flags(f2, b, tid);     // ---- sync 2 (predecessors only) ----

    // ---- Phase D: cross-block B scan; lanes >= b garbage, unused ----
    float hP = 1.f, hQ = 0.f;
    {
        const int ix = 4 * tid;
#pragma unroll
        for (int q = 0; q < 4; ++q) {
            float gp = AT_LOAD(&scrP[ix + q]);
            float gq = AT_LOAD(&scrQ[ix + q]);
            hQ = gp * hQ + gq;
            hP = hP * gp;
        }
    }
    sA[tid] = hP; sB[tid] = hQ;
    __syncthreads();
    for (int s = 1; s < TPB; s <<= 1) {
        float pp = 0.f, pc = 0.f;
        const bool has = (tid >= s);
        if (has) { pp = sA[tid - s]; pc = sB[tid - s]; }
        __syncthreads();
        if (has) {
            float np = pp * hP;
            float nc = hP * pc + hQ;
            hP = np; hQ = nc;
            sA[tid] = hP; sB[tid] = hQ;
        }
        __syncthreads();
    }
    float Bst;
    {
        float fP = 1.f, fQ = 0.f;
        const int g = b >> 2, r = b & 3;
        if (g > 0) { fP = sA[g - 1]; fQ = sB[g - 1]; }
        for (int q = 0; q < r; ++q) {
            float gp = AT_LOAD(&scrP[4 * g + q]);
            float gq = AT_LOAD(&scrQ[4 * g + q]);
            fQ = gp * fQ + gq;
            fP *= gp;
        }
        Bst = fP * 1.0f + fQ;    // B_INIT = 1.0 -> B at block start
        Bst = eP * Bst + eQ;     // B at thread start
    }

    // ---- Phase E: add (1-k)*k^j*B_start, coalesced store ----
    float f = omk * Bst;
    if (m == ITEMS) {
#pragma unroll
        for (int j = 0; j < ITEMS; ++j) { lds_d[toff + j] += f; f *= k; }
    } else {
        for (int j = 0; j < m; ++j) { lds_d[toff + j] += f; f *= k; }
    }
    __syncthreads();
    {
        float4* out4 = (float4*)out;
        const float4* l4 = (const float4*)lds_d;
        for (int i = tid; i < TILE / 4; i += TPB) {
            int e = gbase + 4 * i;
            if (e < T) out4[(gbase >> 2) + i] = l4[i];   // T%4==0, gbase%4==0
        }
    }
}

extern "C" void kernel_launch(void* const* d_in, const int* in_sizes, int n_in,
                              void* d_out, int out_size, void* d_ws, size_t ws_size,
                              hipStream_t stream) {
    const float* x    = (const float*)d_in[0];
    const float* BFI  = (const float*)d_in[1];
    const float* K    = (const float*)d_in[2];
    const float* Smax = (const float*)d_in[3];
    float* out = (float*)d_out;
    float* ws  = (float*)d_ws;   // needs 28 KB
    int T = out_size;            // 8,000,000

    void* args[] = { (void*)&x, (void*)&BFI, (void*)&K, (void*)&Smax,
                     (void*)&out, (void*)&ws, (void*)&T };
    hipLaunchCooperativeKernel(awbm_kernel, dim3(GRID), dim3(TPB), args, 0, stream);
}

// Round 3
// 149.894 us; speedup vs baseline: 3.5028x; 1.6028x over previous
//
#include <hip/hip_runtime.h>

constexpr int TPB   = 256;
constexpr int ITEMS = 31;
constexpr int TILE  = TPB * ITEMS;   // 7936 elements per block
constexpr int GRID  = 1024;          // GRID*TILE = 8,126,464 >= 8,000,000
constexpr unsigned MAGIC = 0xC0DE600Du;   // != 0xAAAAAAAA ws-poison, != 0

// Clamp monoid: f(x) = min(max(x + A, B), C). compose(l, r) (l applied first):
//   A = Al + Ar;  B = max(Bl + Ar, Br);  C = min(max(Cl + Ar, Br), Cr)
// Affine monoid: f(x) = P*x + Q. compose(l, r): P = Pl*Pr; Q = Pr*Ql + Qr
//
// Sync protocol (fence-free): ALL scratch traffic is relaxed agent-scope
// atomics (sc0/sc1 -> served at the MALL coherence point; never cached stale;
// no buffer_wbl2 / buffer_inv needed). Producer orders data-before-flag with
// s_waitcnt vmcnt(0); consumer's data loads issue after the flag branch
// resolves (in-order wave issue). Compiler reordering blocked by signal fences.

#define AT_LOAD(p)    __hip_atomic_load((p), __ATOMIC_RELAXED, __HIP_MEMORY_SCOPE_AGENT)
#define AT_STORE(p,v) __hip_atomic_store((p), (v), __ATOMIC_RELAXED, __HIP_MEMORY_SCOPE_AGENT)

__global__ __launch_bounds__(TPB, 4)
void awbm_kernel(const float* __restrict__ x,
                 const float* __restrict__ pBFI,
                 const float* __restrict__ pK,
                 const float* __restrict__ pSmax,
                 float* __restrict__ out,
                 float* __restrict__ ws,
                 int T)
{
    __shared__ __align__(16) float lds_d[TILE];
    __shared__ float sm[12];    // 4 wave-aggregates (3 floats clamp / 2 affine)

    const int tid  = threadIdx.x;
    const int lane = tid & 63;
    const int wv   = tid >> 6;
    const int b    = blockIdx.x;

    const float bfi  = pBFI[0];
    const float k    = pK[0];
    const float smax = pSmax[0];
    const float omb  = 1.0f - bfi;
    const float omk  = 1.0f - k;
    const float INF  = __builtin_inff();

    float*    scrA = ws;
    float*    scrB = ws + GRID;
    float*    scrC = ws + 2 * GRID;
    float*    scrP = ws + 3 * GRID;
    float*    scrQ = ws + 4 * GRID;
    unsigned* f1   = (unsigned*)(ws + 5 * GRID);
    unsigned* f2   = (unsigned*)(ws + 6 * GRID);

    const int gbase = b * TILE;

    // ---- stage x -> d in LDS (the ONLY read of x) ----
    {
        const float4* x4 = (const float4*)x;   // two (p,e) pairs per float4
        float2* d2 = (float2*)lds_d;
        for (int i = tid; i < TILE / 2; i += TPB) {
            int e = gbase + 2 * i;
            float2 dv; dv.x = 0.f; dv.y = 0.f;
            if (e < T) {                       // T even => pair fully in-range
                float4 v = x4[(gbase >> 1) + i];
                dv.x = v.x - v.y;
                dv.y = v.z - v.w;
            }
            d2[i] = dv;
        }
    }
    __syncthreads();   // S1

    const int toff = tid * ITEMS;
    int m = T - gbase - toff;
    m = m < 0 ? 0 : (m > ITEMS ? ITEMS : m);

    // ---- Phase A: per-thread clamp fold ----
    float rA = 0.f, rB = -INF, rC = INF;
    if (m == ITEMS) {
#pragma unroll
        for (int j = 0; j < ITEMS; ++j) {
            float d = lds_d[toff + j];
            rA += d;
            rB = fmaxf(rB + d, 0.f);
            rC = fminf(fmaxf(rC + d, 0.f), smax);
        }
    } else {
        for (int j = 0; j < m; ++j) {
            float d = lds_d[toff + j];
            rA += d;
            rB = fmaxf(rB + d, 0.f);
            rC = fminf(fmaxf(rC + d, 0.f), smax);
        }
    }
    // wave inclusive scan (shfl, no barriers)
#pragma unroll
    for (int s = 1; s < 64; s <<= 1) {
        float pA = __shfl_up(rA, s, 64), pB = __shfl_up(rB, s, 64), pC = __shfl_up(rC, s, 64);
        if (lane >= s) {
            float nA = pA + rA, nB = fmaxf(pB + rA, rB), nC = fminf(fmaxf(pC + rA, rB), rC);
            rA = nA; rB = nB; rC = nC;
        }
    }
    if (lane == 63) { sm[wv * 3] = rA; sm[wv * 3 + 1] = rB; sm[wv * 3 + 2] = rC; }
    __syncthreads();   // S2
    float wA = 0.f, wB = -INF, wC = INF;       // exclusive cross-wave prefix
    for (int i = 0; i < wv; ++i) {
        float a = sm[i * 3], bb = sm[i * 3 + 1], c = sm[i * 3 + 2];
        float nA = wA + a, nB = fmaxf(wB + a, bb), nC = fminf(fmaxf(wC + a, bb), c);
        wA = nA; wB = nB; wC = nC;
    }
    {   // thread inclusive across block
        float nA = wA + rA, nB = fmaxf(wB + rA, rB), nC = fminf(fmaxf(wC + rA, rB), rC);
        rA = nA; rB = nB; rC = nC;
    }
    if (tid == TPB - 1) {                      // block aggregate -> publish
        AT_STORE(&scrA[b], rA); AT_STORE(&scrB[b], rB); AT_STORE(&scrC[b], rC);
        __atomic_signal_fence(__ATOMIC_SEQ_CST);
        __builtin_amdgcn_s_waitcnt(0);         // data visible at MALL
        __atomic_signal_fence(__ATOMIC_SEQ_CST);
        AT_STORE(&f1[b], MAGIC);
    }
    // thread-exclusive in-block prefix
    float eA, eB, eC;
    {
        float pA = __shfl_up(rA, 1, 64), pB = __shfl_up(rB, 1, 64), pC = __shfl_up(rC, 1, 64);
        eA = (lane == 0) ? wA : pA;
        eB = (lane == 0) ? wB : pB;
        eC = (lane == 0) ? wC : pC;
    }

    // ---- cross-block fold over [0,b): poll predecessors' flags, then fold ----
    const int base4 = 4 * tid;
    unsigned need = 0;
#pragma unroll
    for (int q = 0; q < 4; ++q) if (base4 + q < b) need |= (1u << q);
    {
        unsigned pend = need;
        while (pend) {
            unsigned got = 0;
#pragma unroll
            for (int q = 0; q < 4; ++q)
                if ((pend >> q) & 1u)
                    if (AT_LOAD(&f1[base4 + q]) == MAGIC) got |= (1u << q);
            pend &= ~got;
            if (pend) __builtin_amdgcn_s_sleep(1);
        }
    }
    __atomic_signal_fence(__ATOMIC_ACQUIRE);   // compiler: no hoist of data loads
    float cA = 0.f, cB = -INF, cC = INF;
#pragma unroll
    for (int q = 0; q < 4; ++q) {
        if ((need >> q) & 1u) {
            float ga = AT_LOAD(&scrA[base4 + q]);
            float gb = AT_LOAD(&scrB[base4 + q]);
            float gc = AT_LOAD(&scrC[base4 + q]);
            float nA = cA + ga, nB = fmaxf(cB + ga, gb), nC = fminf(fmaxf(cC + ga, gb), gc);
            cA = nA; cB = nB; cC = nC;
        }
    }
#pragma unroll
    for (int s = 1; s < 64; s <<= 1) {         // ordered wave fold (contiguous chunks)
        float oa = __shfl_down(cA, s, 64), ob = __shfl_down(cB, s, 64), oc = __shfl_down(cC, s, 64);
        float nA = cA + oa, nB = fmaxf(cB + oa, ob), nC = fminf(fmaxf(cC + oa, ob), oc);
        cA = nA; cB = nB; cC = nC;
    }
    __syncthreads();   // S3: S2-phase reads of sm done
    if (lane == 0) { sm[wv * 3] = cA; sm[wv * 3 + 1] = cB; sm[wv * 3 + 2] = cC; }
    __syncthreads();   // S4
    float S;
    {
        float FA = 0.f, FB = -INF, FC = INF;
        for (int i = 0; i < 4; ++i) {
            float a = sm[i * 3], bb = sm[i * 3 + 1], c = sm[i * 3 + 2];
            float nA = FA + a, nB = fmaxf(FB + a, bb), nC = fminf(fmaxf(FC + a, bb), c);
            FA = nA; FB = nB; FC = nC;
        }
        S = fminf(fmaxf(0.5f + FA, FB), FC);   // S_INIT = 0.5 -> S at block start
        S = fminf(fmaxf(S + eA, eB), eC);      // S at thread start
    }

    // ---- Phase C: sequential walk; partial outflow into LDS; affine fold ----
    float p = 1.f, c = 0.f;
    if (m == ITEMS) {
#pragma unroll
        for (int j = 0; j < ITEMS; ++j) {
            float d  = lds_d[toff + j];
            float S1 = fmaxf(S + d, 0.f);
            float ex = fmaxf(S1 - smax, 0.f);
            S = S1 - ex;
            float w = c + bfi * ex;
            lds_d[toff + j] = omb * ex + omk * w;
            c = k * w;
            p *= k;
        }
    } else {
        for (int j = 0; j < m; ++j) {
            float d  = lds_d[toff + j];
            float S1 = fmaxf(S + d, 0.f);
            float ex = fmaxf(S1 - smax, 0.f);
            S = S1 - ex;
            float w = c + bfi * ex;
            lds_d[toff + j] = omb * ex + omk * w;
            c = k * w;
        }
        // p for skipped items stays k^m composed with identity: only j<m steps happened
        for (int j = 0; j < m; ++j) p *= k;
    }
    // wave inclusive affine scan
#pragma unroll
    for (int s = 1; s < 64; s <<= 1) {
        float pp = __shfl_up(p, s, 64), pc = __shfl_up(c, s, 64);
        if (lane >= s) {
            float nq = p * pc + c;   // Q = Pr*Ql + Qr
            p = pp * p;
            c = nq;
        }
    }
    __syncthreads();   // S5: S4-phase reads of sm done
    if (lane == 63) { sm[wv * 2] = p; sm[wv * 2 + 1] = c; }
    __syncthreads();   // S6
    float wP = 1.f, wQ = 0.f;                  // exclusive cross-wave prefix
    for (int i = 0; i < wv; ++i) {
        float gp = sm[i * 2], gq = sm[i * 2 + 1];
        wQ = gp * wQ + gq;
        wP = wP * gp;
    }
    {   // thread inclusive across block
        float nq = p * wQ + c;
        p = wP * p;
        c = nq;
    }
    if (tid == TPB - 1) {                      // block affine aggregate -> publish
        AT_STORE(&scrP[b], p); AT_STORE(&scrQ[b], c);
        __atomic_signal_fence(__ATOMIC_SEQ_CST);
        __builtin_amdgcn_s_waitcnt(0);
        __atomic_signal_fence(__ATOMIC_SEQ_CST);
        AT_STORE(&f2[b], MAGIC);
    }
    float eP, eQ;
    {
        float pp = __shfl_up(p, 1, 64), pc = __shfl_up(c, 1, 64);
        eP = (lane == 0) ? wP : pp;
        eQ = (lane == 0) ? wQ : pc;
    }

    // ---- cross-block affine fold over [0,b) ----
    {
        unsigned pend = need;
        while (pend) {
            unsigned got = 0;
#pragma unroll
            for (int q = 0; q < 4; ++q)
                if ((pend >> q) & 1u)
                    if (AT_LOAD(&f2[base4 + q]) == MAGIC) got |= (1u << q);
            pend &= ~got;
            if (pend) __builtin_amdgcn_s_sleep(1);
        }
    }
    __atomic_signal_fence(__ATOMIC_ACQUIRE);
    float cP = 1.f, cQ = 0.f;
#pragma unroll
    for (int q = 0; q < 4; ++q) {
        if ((need >> q) & 1u) {
            float gp = AT_LOAD(&scrP[base4 + q]);
            float gq = AT_LOAD(&scrQ[base4 + q]);
            cQ = gp * cQ + gq;
            cP = cP * gp;
        }
    }
#pragma unroll
    for (int s = 1; s < 64; s <<= 1) {         // ordered wave fold
        float op = __shfl_down(cP, s, 64), oq = __shfl_down(cQ, s, 64);
        float nq = op * cQ + oq;
        cP = cP * op;
        cQ = nq;
    }
    __syncthreads();   // S7: S6-phase reads of sm done
    if (lane == 0) { sm[wv * 2] = cP; sm[wv * 2 + 1] = cQ; }
    __syncthreads();   // S8
    float Bst;
    {
        float FP = 1.f, FQ = 0.f;
        for (int i = 0; i < 4; ++i) {
            float gp = sm[i * 2], gq = sm[i * 2 + 1];
            FQ = gp * FQ + gq;
            FP = FP * gp;
        }
        Bst = FP * 1.0f + FQ;    // B_INIT = 1.0 -> B at block start
        Bst = eP * Bst + eQ;     // B at thread start
    }

    // ---- Phase E: add (1-k)*k^j*B_start, coalesced store ----
    float f = omk * Bst;
    if (m == ITEMS) {
#pragma unroll
        for (int j = 0; j < ITEMS; ++j) { lds_d[toff + j] += f; f *= k; }
    } else {
        for (int j = 0; j < m; ++j) { lds_d[toff + j] += f; f *= k; }
    }
    __syncthreads();   // S9
    {
        float4* out4 = (float4*)out;
        const float4* l4 = (const float4*)lds_d;
        for (int i = tid; i < TILE / 4; i += TPB) {
            int e = gbase + 4 * i;
            if (e < T) out4[(gbase >> 2) + i] = l4[i];   // T%4==0
        }
    }
}

extern "C" void kernel_launch(void* const* d_in, const int* in_sizes, int n_in,
                              void* d_out, int out_size, void* d_ws, size_t ws_size,
                              hipStream_t stream) {
    const float* x    = (const float*)d_in[0];
    const float* BFI  = (const float*)d_in[1];
    const float* K    = (const float*)d_in[2];
    const float* Smax = (const float*)d_in[3];
    float* out = (float*)d_out;
    float* ws  = (float*)d_ws;   // needs 28 KB
    int T = out_size;            // 8,000,000

    void* args[] = { (void*)&x, (void*)&BFI, (void*)&K, (void*)&Smax,
                     (void*)&out, (void*)&ws, (void*)&T };
    hipLaunchCooperativeKernel(awbm_kernel, dim3(GRID), dim3(TPB), args, 0, stream);
}

// Round 4
// 141.671 us; speedup vs baseline: 3.7061x; 1.0580x over previous
//
#include <hip/hip_runtime.h>

constexpr int TPB   = 256;
constexpr int ITEMS = 31;
constexpr int TILE  = TPB * ITEMS;   // 7936 elements per block
constexpr int GRID  = 1024;          // GRID*TILE = 8,126,464 >= 8,000,000
constexpr unsigned MAGIC = 0xC0DE600Du;   // != 0xAAAAAAAA ws-poison, != 0

// Clamp monoid: f(x) = min(max(x + A, B), C). compose(l, r) (l applied first):
//   A = Al + Ar;  B = max(Bl + Ar, Br);  C = min(max(Cl + Ar, Br), Cr)
// Affine monoid: f(x) = P*x + Q. compose(l, r): P = Pl*Pr; Q = Pr*Ql + Qr
//
// Deadlock-freedom WITHOUT cooperative launch: virtual block id from a global
// atomic ticket => vid order == block start order; started blocks are never
// preempted; every block publishes its aggregate BEFORE waiting; waits target
// only lower vids => all waited-on blocks are running/finished and publish
// unconditionally. (CUB decoupled-lookback argument.)
//
// Sync protocol (fence-free): ALL scratch traffic is relaxed agent-scope
// atomics (served at the coherence point; never cached stale). Producer orders
// data-before-flag with s_waitcnt vmcnt(0); consumer's data loads issue after
// the flag poll resolves. Compiler reordering blocked by signal fences.

#define AT_LOAD(p)    __hip_atomic_load((p), __ATOMIC_RELAXED, __HIP_MEMORY_SCOPE_AGENT)
#define AT_STORE(p,v) __hip_atomic_store((p), (v), __ATOMIC_RELAXED, __HIP_MEMORY_SCOPE_AGENT)

__global__ __launch_bounds__(TPB, 4)
void awbm_kernel(const float* __restrict__ x,
                 const float* __restrict__ pBFI,
                 const float* __restrict__ pK,
                 const float* __restrict__ pSmax,
                 float* __restrict__ out,
                 float* __restrict__ ws,
                 int T)
{
    __shared__ __align__(16) float lds_d[TILE];
    __shared__ float sm[12];    // 4 wave-aggregates (3 floats clamp / 2 affine)
    __shared__ unsigned svid;

    const int tid  = threadIdx.x;
    const int lane = tid & 63;
    const int wv   = tid >> 6;

    float*    scrA   = ws;
    float*    scrB   = ws + GRID;
    float*    scrC   = ws + 2 * GRID;
    float*    scrP   = ws + 3 * GRID;
    float*    scrQ   = ws + 4 * GRID;
    unsigned* f1     = (unsigned*)(ws + 5 * GRID);
    unsigned* f2     = (unsigned*)(ws + 6 * GRID);
    unsigned* ticket = (unsigned*)(ws + 7 * GRID);

    if (tid == 0)
        svid = __hip_atomic_fetch_add(ticket, 1u, __ATOMIC_RELAXED, __HIP_MEMORY_SCOPE_AGENT);

    const float bfi  = pBFI[0];
    const float k    = pK[0];
    const float smax = pSmax[0];
    const float omb  = 1.0f - bfi;
    const float omk  = 1.0f - k;
    const float INF  = __builtin_inff();

    __syncthreads();   // S0: svid visible
    const int b     = (int)svid;
    const int gbase = b * TILE;

    // ---- stage x -> d in LDS (the ONLY read of x) ----
    {
        const float4* x4 = (const float4*)x;   // two (p,e) pairs per float4
        float2* d2 = (float2*)lds_d;
        for (int i = tid; i < TILE / 2; i += TPB) {
            int e = gbase + 2 * i;
            float2 dv; dv.x = 0.f; dv.y = 0.f;
            if (e < T) {                       // T even => pair fully in-range
                float4 v = x4[(gbase >> 1) + i];
                dv.x = v.x - v.y;
                dv.y = v.z - v.w;
            }
            d2[i] = dv;
        }
    }
    __syncthreads();   // S1

    const int toff = tid * ITEMS;
    int m = T - gbase - toff;
    m = m < 0 ? 0 : (m > ITEMS ? ITEMS : m);

    // ---- Phase A: per-thread clamp fold ----
    float rA = 0.f, rB = -INF, rC = INF;
    if (m == ITEMS) {
#pragma unroll
        for (int j = 0; j < ITEMS; ++j) {
            float d = lds_d[toff + j];
            rA += d;
            rB = fmaxf(rB + d, 0.f);
            rC = fminf(fmaxf(rC + d, 0.f), smax);
        }
    } else {
        for (int j = 0; j < m; ++j) {
            float d = lds_d[toff + j];
            rA += d;
            rB = fmaxf(rB + d, 0.f);
            rC = fminf(fmaxf(rC + d, 0.f), smax);
        }
    }
    // wave inclusive scan (shfl, no barriers)
#pragma unroll
    for (int s = 1; s < 64; s <<= 1) {
        float pA = __shfl_up(rA, s, 64), pB = __shfl_up(rB, s, 64), pC = __shfl_up(rC, s, 64);
        if (lane >= s) {
            float nA = pA + rA, nB = fmaxf(pB + rA, rB), nC = fminf(fmaxf(pC + rA, rB), rC);
            rA = nA; rB = nB; rC = nC;
        }
    }
    if (lane == 63) { sm[wv * 3] = rA; sm[wv * 3 + 1] = rB; sm[wv * 3 + 2] = rC; }
    __syncthreads();   // S2
    float wA = 0.f, wB = -INF, wC = INF;       // exclusive cross-wave prefix
    for (int i = 0; i < wv; ++i) {
        float a = sm[i * 3], bb = sm[i * 3 + 1], c = sm[i * 3 + 2];
        float nA = wA + a, nB = fmaxf(wB + a, bb), nC = fminf(fmaxf(wC + a, bb), c);
        wA = nA; wB = nB; wC = nC;
    }
    {   // thread inclusive across block
        float nA = wA + rA, nB = fmaxf(wB + rA, rB), nC = fminf(fmaxf(wC + rA, rB), rC);
        rA = nA; rB = nB; rC = nC;
    }
    if (tid == TPB - 1) {                      // block aggregate -> publish
        AT_STORE(&scrA[b], rA); AT_STORE(&scrB[b], rB); AT_STORE(&scrC[b], rC);
        __atomic_signal_fence(__ATOMIC_SEQ_CST);
        __builtin_amdgcn_s_waitcnt(0);         // data visible at coherence point
        __atomic_signal_fence(__ATOMIC_SEQ_CST);
        AT_STORE(&f1[b], MAGIC);
    }
    // thread-exclusive in-block prefix
    float eA, eB, eC;
    {
        float pA = __shfl_up(rA, 1, 64), pB = __shfl_up(rB, 1, 64), pC = __shfl_up(rC, 1, 64);
        eA = (lane == 0) ? wA : pA;
        eB = (lane == 0) ? wB : pB;
        eC = (lane == 0) ? wC : pC;
    }

    // ---- cross-block fold over [0,b): poll predecessors' flags, then fold ----
    const int base4 = 4 * tid;
    unsigned need = 0;
#pragma unroll
    for (int q = 0; q < 4; ++q) if (base4 + q < b) need |= (1u << q);
    {
        unsigned pend = need;
        while (pend) {
            unsigned got = 0;
#pragma unroll
            for (int q = 0; q < 4; ++q)
                if ((pend >> q) & 1u)
                    if (AT_LOAD(&f1[base4 + q]) == MAGIC) got |= (1u << q);
            pend &= ~got;
            if (pend) __builtin_amdgcn_s_sleep(1);
        }
    }
    __atomic_signal_fence(__ATOMIC_ACQUIRE);   // compiler: no hoist of data loads
    float cA = 0.f, cB = -INF, cC = INF;
#pragma unroll
    for (int q = 0; q < 4; ++q) {
        if ((need >> q) & 1u) {
            float ga = AT_LOAD(&scrA[base4 + q]);
            float gb = AT_LOAD(&scrB[base4 + q]);
            float gc = AT_LOAD(&scrC[base4 + q]);
            float nA = cA + ga, nB = fmaxf(cB + ga, gb), nC = fminf(fmaxf(cC + ga, gb), gc);
            cA = nA; cB = nB; cC = nC;
        }
    }
#pragma unroll
    for (int s = 1; s < 64; s <<= 1) {         // ordered wave fold (contiguous chunks)
        float oa = __shfl_down(cA, s, 64), ob = __shfl_down(cB, s, 64), oc = __shfl_down(cC, s, 64);
        float nA = cA + oa, nB = fmaxf(cB + oa, ob), nC = fminf(fmaxf(cC + oa, ob), oc);
        cA = nA; cB = nB; cC = nC;
    }
    __syncthreads();   // S3: S2-phase reads of sm done
    if (lane == 0) { sm[wv * 3] = cA; sm[wv * 3 + 1] = cB; sm[wv * 3 + 2] = cC; }
    __syncthreads();   // S4
    float S;
    {
        float FA = 0.f, FB = -INF, FC = INF;
        for (int i = 0; i < 4; ++i) {
            float a = sm[i * 3], bb = sm[i * 3 + 1], c = sm[i * 3 + 2];
            float nA = FA + a, nB = fmaxf(FB + a, bb), nC = fminf(fmaxf(FC + a, bb), c);
            FA = nA; FB = nB; FC = nC;
        }
        S = fminf(fmaxf(0.5f + FA, FB), FC);   // S_INIT = 0.5 -> S at block start
        S = fminf(fmaxf(S + eA, eB), eC);      // S at thread start
    }

    // ---- Phase C: sequential walk; partial outflow into LDS; affine fold ----
    float p = 1.f, c = 0.f;
    if (m == ITEMS) {
#pragma unroll
        for (int j = 0; j < ITEMS; ++j) {
            float d  = lds_d[toff + j];
            float S1 = fmaxf(S + d, 0.f);
            float ex = fmaxf(S1 - smax, 0.f);
            S = S1 - ex;
            float w = c + bfi * ex;
            lds_d[toff + j] = omb * ex + omk * w;
            c = k * w;
            p *= k;
        }
    } else {
        for (int j = 0; j < m; ++j) {
            float d  = lds_d[toff + j];
            float S1 = fmaxf(S + d, 0.f);
            float ex = fmaxf(S1 - smax, 0.f);
            S = S1 - ex;
            float w = c + bfi * ex;
            lds_d[toff + j] = omb * ex + omk * w;
            c = k * w;
            p *= k;
        }
    }
    // wave inclusive affine scan
#pragma unroll
    for (int s = 1; s < 64; s <<= 1) {
        float pp = __shfl_up(p, s, 64), pc = __shfl_up(c, s, 64);
        if (lane >= s) {
            float nq = p * pc + c;   // Q = Pr*Ql + Qr
            p = pp * p;
            c = nq;
        }
    }
    __syncthreads();   // S5: S4-phase reads of sm done
    if (lane == 63) { sm[wv * 2] = p; sm[wv * 2 + 1] = c; }
    __syncthreads();   // S6
    float wP = 1.f, wQ = 0.f;                  // exclusive cross-wave prefix
    for (int i = 0; i < wv; ++i) {
        float gp = sm[i * 2], gq = sm[i * 2 + 1];
        wQ = gp * wQ + gq;
        wP = wP * gp;
    }
    {   // thread inclusive across block
        float nq = p * wQ + c;
        p = wP * p;
        c = nq;
    }
    if (tid == TPB - 1) {                      // block affine aggregate -> publish
        AT_STORE(&scrP[b], p); AT_STORE(&scrQ[b], c);
        __atomic_signal_fence(__ATOMIC_SEQ_CST);
        __builtin_amdgcn_s_waitcnt(0);
        __atomic_signal_fence(__ATOMIC_SEQ_CST);
        AT_STORE(&f2[b], MAGIC);
    }
    float eP, eQ;
    {
        float pp = __shfl_up(p, 1, 64), pc = __shfl_up(c, 1, 64);
        eP = (lane == 0) ? wP : pp;
        eQ = (lane == 0) ? wQ : pc;
    }

    // ---- cross-block affine fold over [0,b) ----
    {
        unsigned pend = need;
        while (pend) {
            unsigned got = 0;
#pragma unroll
            for (int q = 0; q < 4; ++q)
                if ((pend >> q) & 1u)
                    if (AT_LOAD(&f2[base4 + q]) == MAGIC) got |= (1u << q);
            pend &= ~got;
            if (pend) __builtin_amdgcn_s_sleep(1);
        }
    }
    __atomic_signal_fence(__ATOMIC_ACQUIRE);
    float cP = 1.f, cQ = 0.f;
#pragma unroll
    for (int q = 0; q < 4; ++q) {
        if ((need >> q) & 1u) {
            float gp = AT_LOAD(&scrP[base4 + q]);
            float gq = AT_LOAD(&scrQ[base4 + q]);
            cQ = gp * cQ + gq;
            cP = cP * gp;
        }
    }
#pragma unroll
    for (int s = 1; s < 64; s <<= 1) {         // ordered wave fold
        float op = __shfl_down(cP, s, 64), oq = __shfl_down(cQ, s, 64);
        float nq = op * cQ + oq;
        cP = cP * op;
        cQ = nq;
    }
    __syncthreads();   // S7: S6-phase reads of sm done
    if (lane == 0) { sm[wv * 2] = cP; sm[wv * 2 + 1] = cQ; }
    __syncthreads();   // S8
    float Bst;
    {
        float FP = 1.f, FQ = 0.f;
        for (int i = 0; i < 4; ++i) {
            float gp = sm[i * 2], gq = sm[i * 2 + 1];
            FQ = gp * FQ + gq;
            FP = FP * gp;
        }
        Bst = FP * 1.0f + FQ;    // B_INIT = 1.0 -> B at block start
        Bst = eP * Bst + eQ;     // B at thread start
    }

    // ---- Phase E: add (1-k)*k^j*B_start, coalesced store ----
    float f = omk * Bst;
    if (m == ITEMS) {
#pragma unroll
        for (int j = 0; j < ITEMS; ++j) { lds_d[toff + j] += f; f *= k; }
    } else {
        for (int j = 0; j < m; ++j) { lds_d[toff + j] += f; f *= k; }
    }
    __syncthreads();   // S9
    {
        float4* out4 = (float4*)out;
        const float4* l4 = (const float4*)lds_d;
        for (int i = tid; i < TILE / 4; i += TPB) {
            int e = gbase + 4 * i;
            if (e < T) out4[(gbase >> 2) + i] = l4[i];   // T%4==0
        }
    }
}

extern "C" void kernel_launch(void* const* d_in, const int* in_sizes, int n_in,
                              void* d_out, int out_size, void* d_ws, size_t ws_size,
                              hipStream_t stream) {
    const float* x    = (const float*)d_in[0];
    const float* BFI  = (const float*)d_in[1];
    const float* K    = (const float*)d_in[2];
    const float* Smax = (const float*)d_in[3];
    float* out = (float*)d_out;
    float* ws  = (float*)d_ws;   // needs 28 KB + 4 B
    int T = out_size;            // 8,000,000

    // zero the ticket counter (ws is poisoned 0xAA before every replay);
    // flags poll for MAGIC so poison is a valid "not ready" state.
    hipMemsetAsync((char*)d_ws + 7 * GRID * sizeof(float), 0, sizeof(unsigned), stream);
    awbm_kernel<<<dim3(GRID), dim3(TPB), 0, stream>>>(x, BFI, K, Smax, out, ws, T);
}